// Round 2
// baseline (2382.818 us; speedup 1.0000x reference)
//
#include <hip/hip_runtime.h>
#include <cstdint>
#include <cstddef>

constexpr int Lc = 2, Ec = 8, Hc = 1024, Ic = 2048, Tc = 2048;

typedef __bf16 bf16x8 __attribute__((ext_vector_type(8)));
typedef float f32x4 __attribute__((ext_vector_type(4)));

__device__ __forceinline__ unsigned short f2bf(float f) {
  unsigned u = __builtin_bit_cast(unsigned, f);
  u = (u + 0x7fffu + ((u >> 16) & 1u)) >> 16;
  return (unsigned short)u;
}
__device__ __forceinline__ float bf2f(unsigned short h) {
  unsigned u = (unsigned)h << 16;
  return __builtin_bit_cast(float, u);
}
__device__ __forceinline__ bf16x8 ldfrag(const unsigned short* p) {
  return __builtin_bit_cast(bf16x8, *(const uint4*)p);
}

// ---------------- router ----------------
__global__ void router_kernel(const float* __restrict__ x, const float* __restrict__ rw,
                              float* __restrict__ logits) {
  const int t = blockIdx.x;
  const int tid = threadIdx.x;
  float acc[Ec];
#pragma unroll
  for (int e = 0; e < Ec; ++e) acc[e] = 0.f;
  const float* xr = x + (size_t)t * Hc;
  for (int h = tid; h < Hc; h += 256) {
    const float xv = xr[h];
    const float* w = rw + (size_t)h * Ec;
#pragma unroll
    for (int e = 0; e < Ec; ++e) acc[e] += xv * w[e];
  }
  __shared__ float red[256][Ec];
#pragma unroll
  for (int e = 0; e < Ec; ++e) red[tid][e] = acc[e];
  __syncthreads();
  for (int s = 128; s > 0; s >>= 1) {
    if (tid < s) {
#pragma unroll
      for (int e = 0; e < Ec; ++e) red[tid][e] += red[tid + s][e];
    }
    __syncthreads();
  }
  if (tid < Ec) logits[(size_t)t * Ec + tid] = red[0][tid];
}

// ---------------- top-2 ----------------
__global__ void topk_kernel(const float* __restrict__ logits, int* __restrict__ cnt,
                            int* __restrict__ tokList, float* __restrict__ wList) {
  const int t = blockIdx.x * blockDim.x + threadIdx.x;
  if (t >= Tc) return;
  float l[Ec];
#pragma unroll
  for (int e = 0; e < Ec; ++e) l[e] = logits[(size_t)t * Ec + e];
  float b0 = -3.4e38f, b1 = -3.4e38f;
  int i0 = 0, i1 = 0;
#pragma unroll
  for (int e = 0; e < Ec; ++e) {
    if (l[e] > b0) { b1 = b0; i1 = i0; b0 = l[e]; i0 = e; }
    else if (l[e] > b1) { b1 = l[e]; i1 = e; }
  }
  const float w0 = 1.f / (1.f + expf(b1 - b0));
  const float w1 = 1.f - w0;
  int p0 = atomicAdd(&cnt[i0], 1);
  tokList[i0 * Tc + p0] = t;
  wList[i0 * Tc + p0] = w0;
  int p1 = atomicAdd(&cnt[i1], 1);
  tokList[i1 * Tc + p1] = t;
  wList[i1 * Tc + p1] = w1;
}

__global__ void offsets_kernel(const int* __restrict__ cnt, int* __restrict__ off) {
  if (threadIdx.x == 0) {
    int s = 0;
    for (int e = 0; e < Ec; ++e) { off[e] = s; s += cnt[e]; }
  }
}

// ---------------- fp32 -> (hi,lo) bf16 split (x) ----------------
__global__ void convert_kernel(const float* __restrict__ x, unsigned short* __restrict__ xh,
                               unsigned short* __restrict__ xl) {
  const int i = blockIdx.x * 256 + threadIdx.x;
  const float v = x[i];
  const unsigned short h = f2bf(v);
  xh[i] = h;
  xl[i] = f2bf(v - bf2f(h));
}

// ---------------- weight convert + transpose: src[e][K][N] fp32 -> dst[e][N][K] bf16 ----------------
template <bool SPLIT>
__global__ __launch_bounds__(256) void transW_kernel(const float* __restrict__ src,
                                                     unsigned short* __restrict__ dh,
                                                     unsigned short* __restrict__ dl,
                                                     int K, int N) {
  const int n0 = blockIdx.x * 64, k0 = blockIdx.y * 64, e = blockIdx.z;
  const float* s = src + (size_t)e * K * N;
  __shared__ float sT[64][65];  // [n][k]
  const int tid = threadIdx.x;
  const int rr = tid >> 4, cc = (tid & 15) * 4;
#pragma unroll
  for (int p = 0; p < 4; ++p) {
    const int k = p * 16 + rr;
    const float4 v = *(const float4*)(s + (size_t)(k0 + k) * N + n0 + cc);
    sT[cc + 0][k] = v.x;
    sT[cc + 1][k] = v.y;
    sT[cc + 2][k] = v.z;
    sT[cc + 3][k] = v.w;
  }
  __syncthreads();
  unsigned short* dhe = dh + (size_t)e * N * K;
  unsigned short* dle = dl + (size_t)e * N * K;
  const int wr = tid >> 3, wc = (tid & 7) * 8;
#pragma unroll
  for (int p = 0; p < 2; ++p) {
    const int n = p * 32 + wr;
    union { unsigned short s[8]; uint4 u; } hh, ll;
#pragma unroll
    for (int j = 0; j < 8; ++j) {
      const float v = sT[n][wc + j];
      const unsigned short h = f2bf(v);
      hh.s[j] = h;
      if constexpr (SPLIT) ll.s[j] = f2bf(v - bf2f(h));
    }
    *(uint4*)(dhe + (size_t)(n0 + n) * K + k0 + wc) = hh.u;
    if constexpr (SPLIT) *(uint4*)(dle + (size_t)(n0 + n) * K + k0 + wc) = ll.u;
  }
}

// ---------------- gateup GEMM v2: 128x64 tile, bf16 pre-transposed weights ----------------
template <bool SPLIT>
__global__ __launch_bounds__(256) void gateup2_kernel(
    const unsigned short* __restrict__ xh, const unsigned short* __restrict__ xl,
    const unsigned short* __restrict__ Wh, const unsigned short* __restrict__ Wl,
    const int* __restrict__ cnt, const int* __restrict__ off,
    const int* __restrict__ tokList, unsigned short* __restrict__ actH,
    unsigned short* __restrict__ actL) {
  const int e = blockIdx.z;
  const int M = cnt[e];
  const int m0 = blockIdx.x * 128;
  if (m0 >= M) return;
  const int n0 = blockIdx.y * 64;
  const int tid = threadIdx.x;

  __shared__ __align__(16) unsigned short sAh[128][40];
  __shared__ __align__(16) unsigned short sAl[SPLIT ? 128 : 1][40];
  __shared__ __align__(16) unsigned short sGh[64][40];
  __shared__ __align__(16) unsigned short sGl[SPLIT ? 64 : 1][40];
  __shared__ __align__(16) unsigned short sUh[64][40];
  __shared__ __align__(16) unsigned short sUl[SPLIT ? 64 : 1][40];

  const int sr = tid >> 2;       // 0..63
  const int sc = (tid & 3) * 8;  // k chunk (ushorts)
  int ra0 = m0 + sr;      if (ra0 >= M) ra0 = M - 1;
  int ra1 = m0 + sr + 64; if (ra1 >= M) ra1 = M - 1;
  const size_t a0 = (size_t)tokList[e * Tc + ra0] * Hc + sc;
  const size_t a1 = (size_t)tokList[e * Tc + ra1] * Hc + sc;
  const size_t gb = ((size_t)e * 4096 + n0 + sr) * Hc + sc;
  const size_t ub = ((size_t)e * 4096 + 2048 + n0 + sr) * Hc + sc;

  f32x4 accg[4][2], accu[4][2];
#pragma unroll
  for (int i = 0; i < 4; ++i)
#pragma unroll
    for (int j = 0; j < 2; ++j) {
      accg[i][j] = f32x4{0.f, 0.f, 0.f, 0.f};
      accu[i][j] = f32x4{0.f, 0.f, 0.f, 0.f};
    }

  const int lane = tid & 63, wv = tid >> 6;
  const int wm = wv >> 1, wn = wv & 1;
  const int q = lane >> 4, mr = lane & 15;

  for (int k0 = 0; k0 < Hc; k0 += 32) {
    // register prefetch (independent of LDS state)
    const uint4 vA0 = *(const uint4*)(xh + a0 + k0);
    const uint4 vA1 = *(const uint4*)(xh + a1 + k0);
    const uint4 vG = *(const uint4*)(Wh + gb + k0);
    const uint4 vU = *(const uint4*)(Wh + ub + k0);
    uint4 vA0l, vA1l, vGl, vUl;
    if constexpr (SPLIT) {
      vA0l = *(const uint4*)(xl + a0 + k0);
      vA1l = *(const uint4*)(xl + a1 + k0);
      vGl = *(const uint4*)(Wl + gb + k0);
      vUl = *(const uint4*)(Wl + ub + k0);
    }
    __syncthreads();
    *(uint4*)&sAh[sr][sc] = vA0;
    *(uint4*)&sAh[sr + 64][sc] = vA1;
    *(uint4*)&sGh[sr][sc] = vG;
    *(uint4*)&sUh[sr][sc] = vU;
    if constexpr (SPLIT) {
      *(uint4*)&sAl[sr][sc] = vA0l;
      *(uint4*)&sAl[sr + 64][sc] = vA1l;
      *(uint4*)&sGl[sr][sc] = vGl;
      *(uint4*)&sUl[sr][sc] = vUl;
    }
    __syncthreads();

    bf16x8 ah[4], al[4];
#pragma unroll
    for (int mt = 0; mt < 4; ++mt) {
      ah[mt] = ldfrag(&sAh[wm * 64 + mt * 16 + mr][q * 8]);
      if constexpr (SPLIT) al[mt] = ldfrag(&sAl[wm * 64 + mt * 16 + mr][q * 8]);
    }
#pragma unroll
    for (int nt = 0; nt < 2; ++nt) {
      const int bc = wn * 32 + nt * 16 + mr;
      const bf16x8 gh = ldfrag(&sGh[bc][q * 8]);
      const bf16x8 uh = ldfrag(&sUh[bc][q * 8]);
      bf16x8 gl, ul;
      if constexpr (SPLIT) {
        gl = ldfrag(&sGl[bc][q * 8]);
        ul = ldfrag(&sUl[bc][q * 8]);
      }
#pragma unroll
      for (int mt = 0; mt < 4; ++mt) {
        accg[mt][nt] = __builtin_amdgcn_mfma_f32_16x16x32_bf16(ah[mt], gh, accg[mt][nt], 0, 0, 0);
        accu[mt][nt] = __builtin_amdgcn_mfma_f32_16x16x32_bf16(ah[mt], uh, accu[mt][nt], 0, 0, 0);
        if constexpr (SPLIT) {
          accg[mt][nt] = __builtin_amdgcn_mfma_f32_16x16x32_bf16(ah[mt], gl, accg[mt][nt], 0, 0, 0);
          accg[mt][nt] = __builtin_amdgcn_mfma_f32_16x16x32_bf16(al[mt], gh, accg[mt][nt], 0, 0, 0);
          accu[mt][nt] = __builtin_amdgcn_mfma_f32_16x16x32_bf16(ah[mt], ul, accu[mt][nt], 0, 0, 0);
          accu[mt][nt] = __builtin_amdgcn_mfma_f32_16x16x32_bf16(al[mt], uh, accu[mt][nt], 0, 0, 0);
        }
      }
    }
  }

  const int valid = M - m0;
  const int rowbase = off[e] + m0;
#pragma unroll
  for (int mt = 0; mt < 4; ++mt)
#pragma unroll
    for (int nt = 0; nt < 2; ++nt)
#pragma unroll
      for (int r = 0; r < 4; ++r) {
        const int lrow = wm * 64 + mt * 16 + q * 4 + r;
        if (lrow < valid) {
          const float g = accg[mt][nt][r];
          const float u = accu[mt][nt][r];
          const float a = (g / (1.f + expf(-g))) * u;
          const int col = n0 + wn * 32 + nt * 16 + mr;
          const size_t idx = (size_t)(rowbase + lrow) * Ic + col;
          const unsigned short h = f2bf(a);
          actH[idx] = h;
          if constexpr (SPLIT) actL[idx] = f2bf(a - bf2f(h));
        }
      }
}

// ---------------- down GEMM v2: 128x64 tile ----------------
template <bool SPLIT>
__global__ __launch_bounds__(256) void down2_kernel(
    const unsigned short* __restrict__ actH, const unsigned short* __restrict__ actL,
    const unsigned short* __restrict__ Wh, const unsigned short* __restrict__ Wl,
    const int* __restrict__ cnt, const int* __restrict__ off,
    const int* __restrict__ tokList, const float* __restrict__ wList,
    float* __restrict__ out) {
  const int e = blockIdx.z;
  const int M = cnt[e];
  const int m0 = blockIdx.x * 128;
  if (m0 >= M) return;
  const int n0 = blockIdx.y * 64;
  const int tid = threadIdx.x;

  __shared__ __align__(16) unsigned short sAh[128][40];
  __shared__ __align__(16) unsigned short sAl[SPLIT ? 128 : 1][40];
  __shared__ __align__(16) unsigned short sBh[64][40];
  __shared__ __align__(16) unsigned short sBl[SPLIT ? 64 : 1][40];
  __shared__ int sTok[128];
  __shared__ float sW[128];

  if (tid < 128) {
    int r = m0 + tid;
    int rc = r < M ? r : M - 1;
    sTok[tid] = tokList[e * Tc + rc];
    sW[tid] = wList[e * Tc + rc];
  }

  const int sr = tid >> 2;
  const int sc = (tid & 3) * 8;
  int ra0 = m0 + sr;      if (ra0 >= M) ra0 = M - 1;
  int ra1 = m0 + sr + 64; if (ra1 >= M) ra1 = M - 1;
  const size_t a0 = (size_t)(off[e] + ra0) * Ic + sc;
  const size_t a1 = (size_t)(off[e] + ra1) * Ic + sc;
  const size_t bb = ((size_t)e * Hc + n0 + sr) * Ic + sc;

  f32x4 acc[4][2];
#pragma unroll
  for (int i = 0; i < 4; ++i)
#pragma unroll
    for (int j = 0; j < 2; ++j) acc[i][j] = f32x4{0.f, 0.f, 0.f, 0.f};

  const int lane = tid & 63, wv = tid >> 6;
  const int wm = wv >> 1, wn = wv & 1;
  const int q = lane >> 4, mr = lane & 15;

  for (int k0 = 0; k0 < Ic; k0 += 32) {
    const uint4 vA0 = *(const uint4*)(actH + a0 + k0);
    const uint4 vA1 = *(const uint4*)(actH + a1 + k0);
    const uint4 vB = *(const uint4*)(Wh + bb + k0);
    uint4 vA0l, vA1l, vBl;
    if constexpr (SPLIT) {
      vA0l = *(const uint4*)(actL + a0 + k0);
      vA1l = *(const uint4*)(actL + a1 + k0);
      vBl = *(const uint4*)(Wl + bb + k0);
    }
    __syncthreads();
    *(uint4*)&sAh[sr][sc] = vA0;
    *(uint4*)&sAh[sr + 64][sc] = vA1;
    *(uint4*)&sBh[sr][sc] = vB;
    if constexpr (SPLIT) {
      *(uint4*)&sAl[sr][sc] = vA0l;
      *(uint4*)&sAl[sr + 64][sc] = vA1l;
      *(uint4*)&sBl[sr][sc] = vBl;
    }
    __syncthreads();

    bf16x8 ah[4], al[4];
#pragma unroll
    for (int mt = 0; mt < 4; ++mt) {
      ah[mt] = ldfrag(&sAh[wm * 64 + mt * 16 + mr][q * 8]);
      if constexpr (SPLIT) al[mt] = ldfrag(&sAl[wm * 64 + mt * 16 + mr][q * 8]);
    }
#pragma unroll
    for (int nt = 0; nt < 2; ++nt) {
      const int bc = wn * 32 + nt * 16 + mr;
      const bf16x8 bh = ldfrag(&sBh[bc][q * 8]);
      bf16x8 bl;
      if constexpr (SPLIT) bl = ldfrag(&sBl[bc][q * 8]);
#pragma unroll
      for (int mt = 0; mt < 4; ++mt) {
        acc[mt][nt] = __builtin_amdgcn_mfma_f32_16x16x32_bf16(ah[mt], bh, acc[mt][nt], 0, 0, 0);
        if constexpr (SPLIT) {
          acc[mt][nt] = __builtin_amdgcn_mfma_f32_16x16x32_bf16(ah[mt], bl, acc[mt][nt], 0, 0, 0);
          acc[mt][nt] = __builtin_amdgcn_mfma_f32_16x16x32_bf16(al[mt], bh, acc[mt][nt], 0, 0, 0);
        }
      }
    }
  }

  const int valid = M - m0;
#pragma unroll
  for (int mt = 0; mt < 4; ++mt)
#pragma unroll
    for (int nt = 0; nt < 2; ++nt)
#pragma unroll
      for (int r = 0; r < 4; ++r) {
        const int lrow = wm * 64 + mt * 16 + q * 4 + r;
        if (lrow < valid) {
          const int col = n0 + wn * 32 + nt * 16 + mr;
          atomicAdd(&out[(size_t)sTok[lrow] * Hc + col], sW[lrow] * acc[mt][nt][r]);
        }
      }
}

// ================= round-1 fallback kernels (known-correct, used if ws too small) =================
template <bool SPLIT>
__global__ __launch_bounds__(256) void gateup_fb(
    const unsigned short* __restrict__ xh, const unsigned short* __restrict__ xl,
    const float* __restrict__ gw, const int* __restrict__ cnt, const int* __restrict__ off,
    const int* __restrict__ tokList, unsigned short* __restrict__ actH,
    unsigned short* __restrict__ actL) {
  const int e = blockIdx.z;
  const int M = cnt[e];
  const int m0 = blockIdx.x * 64;
  if (m0 >= M) return;
  const int n0 = blockIdx.y * 64;
  const float* Bg = gw + (size_t)e * (Hc * 2 * Ic) + n0;
  const int tid = threadIdx.x;
  __shared__ __align__(16) unsigned short sAh[64][40];
  __shared__ __align__(16) unsigned short sAl[SPLIT ? 64 : 1][40];
  __shared__ __align__(16) unsigned short sBgh[64][40];
  __shared__ __align__(16) unsigned short sBgl[SPLIT ? 64 : 1][40];
  __shared__ __align__(16) unsigned short sBuh[64][40];
  __shared__ __align__(16) unsigned short sBul[SPLIT ? 64 : 1][40];
  const int ar = tid >> 2;
  const int ak = (tid & 3) * 8;
  int arow = m0 + ar;
  if (arow >= M) arow = M - 1;
  const size_t abase = (size_t)tokList[e * Tc + arow] * Hc + ak;
  const int bn = tid & 63;
  const int bk = (tid >> 6) * 8;
  const float* bpg = Bg + (size_t)bk * (2 * Ic) + bn;
  const float* bpu = bpg + Ic;
  f32x4 accg[4], accu[4];
#pragma unroll
  for (int i = 0; i < 4; ++i) {
    accg[i] = f32x4{0.f, 0.f, 0.f, 0.f};
    accu[i] = f32x4{0.f, 0.f, 0.f, 0.f};
  }
  const int lane = tid & 63, wv = tid >> 6;
  const int q = lane >> 4, mr = lane & 15;
  const int nc = wv * 16 + (lane & 15);
  for (int k0 = 0; k0 < Hc; k0 += 32) {
    __syncthreads();
    *(uint4*)&sAh[ar][ak] = *(const uint4*)(xh + abase + k0);
    if constexpr (SPLIT) *(uint4*)&sAl[ar][ak] = *(const uint4*)(xl + abase + k0);
    union { unsigned short s[8]; uint4 u; } hg, lg, hu, lu;
#pragma unroll
    for (int j = 0; j < 8; ++j) {
      const float vg = bpg[(size_t)(k0 + j) * (2 * Ic)];
      unsigned short h = f2bf(vg);
      hg.s[j] = h;
      if constexpr (SPLIT) lg.s[j] = f2bf(vg - bf2f(h));
      const float vu = bpu[(size_t)(k0 + j) * (2 * Ic)];
      h = f2bf(vu);
      hu.s[j] = h;
      if constexpr (SPLIT) lu.s[j] = f2bf(vu - bf2f(h));
    }
    *(uint4*)&sBgh[bn][bk] = hg.u;
    *(uint4*)&sBuh[bn][bk] = hu.u;
    if constexpr (SPLIT) {
      *(uint4*)&sBgl[bn][bk] = lg.u;
      *(uint4*)&sBul[bn][bk] = lu.u;
    }
    __syncthreads();
    bf16x8 a_h[4], a_l[4];
#pragma unroll
    for (int mt = 0; mt < 4; ++mt) {
      a_h[mt] = ldfrag(&sAh[mt * 16 + mr][q * 8]);
      if constexpr (SPLIT) a_l[mt] = ldfrag(&sAl[mt * 16 + mr][q * 8]);
    }
    const bf16x8 bgh = ldfrag(&sBgh[nc][q * 8]);
    const bf16x8 buh = ldfrag(&sBuh[nc][q * 8]);
    bf16x8 bgl, bul;
    if constexpr (SPLIT) {
      bgl = ldfrag(&sBgl[nc][q * 8]);
      bul = ldfrag(&sBul[nc][q * 8]);
    }
#pragma unroll
    for (int mt = 0; mt < 4; ++mt) {
      accg[mt] = __builtin_amdgcn_mfma_f32_16x16x32_bf16(a_h[mt], bgh, accg[mt], 0, 0, 0);
      accu[mt] = __builtin_amdgcn_mfma_f32_16x16x32_bf16(a_h[mt], buh, accu[mt], 0, 0, 0);
      if constexpr (SPLIT) {
        accg[mt] = __builtin_amdgcn_mfma_f32_16x16x32_bf16(a_h[mt], bgl, accg[mt], 0, 0, 0);
        accg[mt] = __builtin_amdgcn_mfma_f32_16x16x32_bf16(a_l[mt], bgh, accg[mt], 0, 0, 0);
        accu[mt] = __builtin_amdgcn_mfma_f32_16x16x32_bf16(a_h[mt], bul, accu[mt], 0, 0, 0);
        accu[mt] = __builtin_amdgcn_mfma_f32_16x16x32_bf16(a_l[mt], buh, accu[mt], 0, 0, 0);
      }
    }
  }
  const int valid = M - m0;
  const int rowbase = off[e] + m0;
#pragma unroll
  for (int mt = 0; mt < 4; ++mt)
#pragma unroll
    for (int r = 0; r < 4; ++r) {
      const int row = mt * 16 + q * 4 + r;
      if (row < valid) {
        const float g = accg[mt][r];
        const float u = accu[mt][r];
        const float a = (g / (1.f + expf(-g))) * u;
        const size_t idx = (size_t)(rowbase + row) * Ic + (n0 + nc);
        const unsigned short h = f2bf(a);
        actH[idx] = h;
        if constexpr (SPLIT) actL[idx] = f2bf(a - bf2f(h));
      }
    }
}

template <bool SPLIT>
__global__ __launch_bounds__(256) void down_fb(
    const unsigned short* __restrict__ actH, const unsigned short* __restrict__ actL,
    const float* __restrict__ dw, const int* __restrict__ cnt, const int* __restrict__ off,
    const int* __restrict__ tokList, const float* __restrict__ wList,
    float* __restrict__ out) {
  const int e = blockIdx.z;
  const int M = cnt[e];
  const int m0 = blockIdx.x * 64;
  if (m0 >= M) return;
  const int n0 = blockIdx.y * 64;
  const float* B = dw + (size_t)e * (Ic * Hc) + n0;
  const int tid = threadIdx.x;
  __shared__ __align__(16) unsigned short sAh[64][40];
  __shared__ __align__(16) unsigned short sAl[SPLIT ? 64 : 1][40];
  __shared__ __align__(16) unsigned short sBh[64][40];
  __shared__ __align__(16) unsigned short sBl[SPLIT ? 64 : 1][40];
  __shared__ int sTok[64];
  __shared__ float sW[64];
  if (tid < 64) {
    int r = m0 + tid;
    int rc = r < M ? r : M - 1;
    sTok[tid] = tokList[e * Tc + rc];
    sW[tid] = wList[e * Tc + rc];
  }
  const int ar = tid >> 2;
  const int ak = (tid & 3) * 8;
  int arow = m0 + ar;
  if (arow >= M) arow = M - 1;
  const size_t abase = (size_t)(off[e] + arow) * Ic + ak;
  const int bn = tid & 63;
  const int bk = (tid >> 6) * 8;
  const float* bp = B + (size_t)bk * Hc + bn;
  f32x4 acc[4];
#pragma unroll
  for (int i = 0; i < 4; ++i) acc[i] = f32x4{0.f, 0.f, 0.f, 0.f};
  const int lane = tid & 63, wv = tid >> 6;
  const int q = lane >> 4, mr = lane & 15;
  const int nc = wv * 16 + (lane & 15);
  for (int k0 = 0; k0 < Ic; k0 += 32) {
    __syncthreads();
    *(uint4*)&sAh[ar][ak] = *(const uint4*)(actH + abase + k0);
    if constexpr (SPLIT) *(uint4*)&sAl[ar][ak] = *(const uint4*)(actL + abase + k0);
    union { unsigned short s[8]; uint4 u; } hb, lb;
#pragma unroll
    for (int j = 0; j < 8; ++j) {
      const float v = bp[(size_t)(k0 + j) * Hc];
      const unsigned short h = f2bf(v);
      hb.s[j] = h;
      if constexpr (SPLIT) lb.s[j] = f2bf(v - bf2f(h));
    }
    *(uint4*)&sBh[bn][bk] = hb.u;
    if constexpr (SPLIT) *(uint4*)&sBl[bn][bk] = lb.u;
    __syncthreads();
    bf16x8 a_h[4], a_l[4];
#pragma unroll
    for (int mt = 0; mt < 4; ++mt) {
      a_h[mt] = ldfrag(&sAh[mt * 16 + mr][q * 8]);
      if constexpr (SPLIT) a_l[mt] = ldfrag(&sAl[mt * 16 + mr][q * 8]);
    }
    const bf16x8 b_h = ldfrag(&sBh[nc][q * 8]);
    bf16x8 b_l;
    if constexpr (SPLIT) b_l = ldfrag(&sBl[nc][q * 8]);
#pragma unroll
    for (int mt = 0; mt < 4; ++mt) {
      acc[mt] = __builtin_amdgcn_mfma_f32_16x16x32_bf16(a_h[mt], b_h, acc[mt], 0, 0, 0);
      if constexpr (SPLIT) {
        acc[mt] = __builtin_amdgcn_mfma_f32_16x16x32_bf16(a_h[mt], b_l, acc[mt], 0, 0, 0);
        acc[mt] = __builtin_amdgcn_mfma_f32_16x16x32_bf16(a_l[mt], b_h, acc[mt], 0, 0, 0);
      }
    }
  }
  const int valid = M - m0;
#pragma unroll
  for (int mt = 0; mt < 4; ++mt)
#pragma unroll
    for (int r = 0; r < 4; ++r) {
      const int row = mt * 16 + q * 4 + r;
      if (row < valid) {
        atomicAdd(&out[(size_t)sTok[row] * Hc + (n0 + nc)], sW[row] * acc[mt][r]);
      }
    }
}

// ---------------- host ----------------
extern "C" void kernel_launch(void* const* d_in, const int* in_sizes, int n_in, void* d_out,
                              int out_size, void* d_ws, size_t ws_size, hipStream_t stream) {
  const float* x_in = (const float*)d_in[0];
  const float* rw = (const float*)d_in[1];
  const float* guw = (const float*)d_in[2];
  const float* dnw = (const float*)d_in[3];
  float* out = (float*)d_out;
  float* logits_base = out + (size_t)Tc * Hc;

  uint8_t* w = (uint8_t*)d_ws;
  float* x1 = (float*)w;                     w += (size_t)Tc * Hc * 4;
  unsigned short* xh = (unsigned short*)w;   w += (size_t)Tc * Hc * 2;
  unsigned short* xl = (unsigned short*)w;   w += (size_t)Tc * Hc * 2;
  unsigned short* actH = (unsigned short*)w; w += (size_t)Tc * 2 * Ic * 2;
  unsigned short* actL = (unsigned short*)w; w += (size_t)Tc * 2 * Ic * 2;
  int* tokList = (int*)w;                    w += (size_t)Ec * Tc * 4;
  float* wList = (float*)w;                  w += (size_t)Ec * Tc * 4;
  int* cnt0 = (int*)w;                       w += 64;
  int* cnt1 = (int*)w;                       w += 64;
  int* off = (int*)w;                        w += 64;
  // weight region (reused gu -> dn within a layer, and across layers)
  const size_t GU_SZ = (size_t)Ec * 4096 * Hc;  // elements
  const size_t DN_SZ = (size_t)Ec * Hc * Ic;
  unsigned short* WTh = (unsigned short*)w;
  unsigned short* WTl = WTh + GU_SZ;   // gu layout: lo after hi
  unsigned short* WdTh = WTh;          // dn reuses region
  unsigned short* WdTl = WTh + DN_SZ;
  const size_t required = ((uint8_t*)(WTh + 2 * GU_SZ)) - (uint8_t*)d_ws;

  hipMemsetAsync(cnt0, 0, 192, stream);
  hipMemsetAsync(x1, 0, (size_t)Tc * Hc * 4, stream);
  hipMemsetAsync(out, 0, (size_t)Tc * Hc * 4, stream);

  const float* rw1 = rw + (size_t)Hc * Ec;
  const float* guw1 = guw + (size_t)Ec * Hc * 2 * Ic;
  const float* dnw1 = dnw + (size_t)Ec * Ic * Hc;

  if (ws_size >= required) {
    // ---- layer 0 (split) ----
    router_kernel<<<Tc, 256, 0, stream>>>(x_in, rw, logits_base);
    topk_kernel<<<Tc / 256, 256, 0, stream>>>(logits_base, cnt0, tokList, wList);
    offsets_kernel<<<1, 64, 0, stream>>>(cnt0, off);
    convert_kernel<<<(Tc * Hc) / 256, 256, 0, stream>>>(x_in, xh, xl);
    transW_kernel<true><<<dim3(64, 16, Ec), 256, 0, stream>>>(guw, WTh, WTl, Hc, 2 * Ic);
    gateup2_kernel<true><<<dim3(32, 32, Ec), 256, 0, stream>>>(xh, xl, WTh, WTl, cnt0, off,
                                                               tokList, actH, actL);
    transW_kernel<true><<<dim3(16, 32, Ec), 256, 0, stream>>>(dnw, WdTh, WdTl, Ic, Hc);
    down2_kernel<true><<<dim3(32, 16, Ec), 256, 0, stream>>>(actH, actL, WdTh, WdTl, cnt0, off,
                                                             tokList, wList, x1);
    // ---- layer 1 (plain bf16) ----
    router_kernel<<<Tc, 256, 0, stream>>>(x1, rw1, logits_base + (size_t)Tc * Ec);
    topk_kernel<<<Tc / 256, 256, 0, stream>>>(logits_base + (size_t)Tc * Ec, cnt1, tokList, wList);
    offsets_kernel<<<1, 64, 0, stream>>>(cnt1, off);
    convert_kernel<<<(Tc * Hc) / 256, 256, 0, stream>>>(x1, xh, xl);
    transW_kernel<false><<<dim3(64, 16, Ec), 256, 0, stream>>>(guw1, WTh, WTl, Hc, 2 * Ic);
    gateup2_kernel<false><<<dim3(32, 32, Ec), 256, 0, stream>>>(xh, xl, WTh, WTl, cnt1, off,
                                                                tokList, actH, actL);
    transW_kernel<false><<<dim3(16, 32, Ec), 256, 0, stream>>>(dnw1, WdTh, WdTl, Ic, Hc);
    down2_kernel<false><<<dim3(32, 16, Ec), 256, 0, stream>>>(actH, actL, WdTh, WdTl, cnt1, off,
                                                              tokList, wList, out);
  } else {
    // ---- fallback: round-1 path (no big weight buffer) ----
    router_kernel<<<Tc, 256, 0, stream>>>(x_in, rw, logits_base);
    topk_kernel<<<Tc / 256, 256, 0, stream>>>(logits_base, cnt0, tokList, wList);
    offsets_kernel<<<1, 64, 0, stream>>>(cnt0, off);
    convert_kernel<<<(Tc * Hc) / 256, 256, 0, stream>>>(x_in, xh, xl);
    gateup_fb<true><<<dim3(32, 32, Ec), 256, 0, stream>>>(xh, xl, guw, cnt0, off, tokList, actH, actL);
    down_fb<true><<<dim3(32, 16, Ec), 256, 0, stream>>>(actH, actL, dnw, cnt0, off, tokList, wList, x1);
    router_kernel<<<Tc, 256, 0, stream>>>(x1, rw1, logits_base + (size_t)Tc * Ec);
    topk_kernel<<<Tc / 256, 256, 0, stream>>>(logits_base + (size_t)Tc * Ec, cnt1, tokList, wList);
    offsets_kernel<<<1, 64, 0, stream>>>(cnt1, off);
    convert_kernel<<<(Tc * Hc) / 256, 256, 0, stream>>>(x1, xh, xl);
    gateup_fb<false><<<dim3(32, 32, Ec), 256, 0, stream>>>(xh, xl, guw1, cnt1, off, tokList, actH, actL);
    down_fb<false><<<dim3(32, 16, Ec), 256, 0, stream>>>(actH, actL, dnw1, cnt1, off, tokList, wList, out);
  }
}

// Round 3
// 2331.457 us; speedup vs baseline: 1.0220x; 1.0220x over previous
//
#include <hip/hip_runtime.h>
#include <cstdint>
#include <cstddef>

constexpr int Lc = 2, Ec = 8, Hc = 1024, Ic = 2048, Tc = 2048;

typedef __bf16 bf16x8 __attribute__((ext_vector_type(8)));
typedef float f32x4 __attribute__((ext_vector_type(4)));

__device__ __forceinline__ unsigned short f2bf(float f) {
  unsigned u = __builtin_bit_cast(unsigned, f);
  u = (u + 0x7fffu + ((u >> 16) & 1u)) >> 16;
  return (unsigned short)u;
}
__device__ __forceinline__ float bf2f(unsigned short h) {
  unsigned u = (unsigned)h << 16;
  return __builtin_bit_cast(float, u);
}
__device__ __forceinline__ bf16x8 ldfrag(const unsigned short* p) {
  return __builtin_bit_cast(bf16x8, *(const uint4*)p);
}

// async global->LDS, 16B per lane; LDS dest = wave-uniform base + lane*16
typedef const __attribute__((address_space(1))) unsigned int* gas_t;
typedef __attribute__((address_space(3))) unsigned int* las_t;
__device__ __forceinline__ void gl2lds16(const void* g, void* l) {
  __builtin_amdgcn_global_load_lds((gas_t)g, (las_t)l, 16, 0, 0);
}

// ---------------- router ----------------
__global__ void router_kernel(const float* __restrict__ x, const float* __restrict__ rw,
                              float* __restrict__ logits) {
  const int t = blockIdx.x;
  const int tid = threadIdx.x;
  float acc[Ec];
#pragma unroll
  for (int e = 0; e < Ec; ++e) acc[e] = 0.f;
  const float* xr = x + (size_t)t * Hc;
  for (int h = tid; h < Hc; h += 256) {
    const float xv = xr[h];
    const float* w = rw + (size_t)h * Ec;
#pragma unroll
    for (int e = 0; e < Ec; ++e) acc[e] += xv * w[e];
  }
  __shared__ float red[256][Ec];
#pragma unroll
  for (int e = 0; e < Ec; ++e) red[tid][e] = acc[e];
  __syncthreads();
  for (int s = 128; s > 0; s >>= 1) {
    if (tid < s) {
#pragma unroll
      for (int e = 0; e < Ec; ++e) red[tid][e] += red[tid + s][e];
    }
    __syncthreads();
  }
  if (tid < Ec) logits[(size_t)t * Ec + tid] = red[0][tid];
}

// ---------------- top-2 ----------------
__global__ void topk_kernel(const float* __restrict__ logits, int* __restrict__ cnt,
                            int* __restrict__ tokList, float* __restrict__ wList) {
  const int t = blockIdx.x * blockDim.x + threadIdx.x;
  if (t >= Tc) return;
  float l[Ec];
#pragma unroll
  for (int e = 0; e < Ec; ++e) l[e] = logits[(size_t)t * Ec + e];
  float b0 = -3.4e38f, b1 = -3.4e38f;
  int i0 = 0, i1 = 0;
#pragma unroll
  for (int e = 0; e < Ec; ++e) {
    if (l[e] > b0) { b1 = b0; i1 = i0; b0 = l[e]; i0 = e; }
    else if (l[e] > b1) { b1 = l[e]; i1 = e; }
  }
  const float w0 = 1.f / (1.f + expf(b1 - b0));
  const float w1 = 1.f - w0;
  int p0 = atomicAdd(&cnt[i0], 1);
  tokList[i0 * Tc + p0] = t;
  wList[i0 * Tc + p0] = w0;
  int p1 = atomicAdd(&cnt[i1], 1);
  tokList[i1 * Tc + p1] = t;
  wList[i1 * Tc + p1] = w1;
}

__global__ void offsets_kernel(const int* __restrict__ cnt, int* __restrict__ off) {
  if (threadIdx.x == 0) {
    int s = 0;
    for (int e = 0; e < Ec; ++e) { off[e] = s; s += cnt[e]; }
  }
}

// ---------------- fp32 -> (hi,lo) bf16 split (x) ----------------
__global__ void convert_kernel(const float* __restrict__ x, unsigned short* __restrict__ xh,
                               unsigned short* __restrict__ xl) {
  const int i = blockIdx.x * 256 + threadIdx.x;
  const float v = x[i];
  const unsigned short h = f2bf(v);
  xh[i] = h;
  xl[i] = f2bf(v - bf2f(h));
}

// ---------------- weight convert + transpose: src[e][K][N] fp32 -> dst[e][N][K] bf16 ----------------
template <bool SPLIT>
__global__ __launch_bounds__(256) void transW_kernel(const float* __restrict__ src,
                                                     unsigned short* __restrict__ dh,
                                                     unsigned short* __restrict__ dl,
                                                     int K, int N) {
  const int n0 = blockIdx.x * 64, k0 = blockIdx.y * 64, e = blockIdx.z;
  const float* s = src + (size_t)e * K * N;
  __shared__ float sT[64][65];  // [n][k]
  const int tid = threadIdx.x;
  const int rr = tid >> 4, cc = (tid & 15) * 4;
#pragma unroll
  for (int p = 0; p < 4; ++p) {
    const int k = p * 16 + rr;
    const float4 v = *(const float4*)(s + (size_t)(k0 + k) * N + n0 + cc);
    sT[cc + 0][k] = v.x;
    sT[cc + 1][k] = v.y;
    sT[cc + 2][k] = v.z;
    sT[cc + 3][k] = v.w;
  }
  __syncthreads();
  unsigned short* dhe = dh + (size_t)e * N * K;
  unsigned short* dle = dl + (size_t)e * N * K;
  const int wr = tid >> 3, wc = (tid & 7) * 8;
#pragma unroll
  for (int p = 0; p < 2; ++p) {
    const int n = p * 32 + wr;
    union { unsigned short s[8]; uint4 u; } hh, ll;
#pragma unroll
    for (int j = 0; j < 8; ++j) {
      const float v = sT[n][wc + j];
      const unsigned short h = f2bf(v);
      hh.s[j] = h;
      if constexpr (SPLIT) ll.s[j] = f2bf(v - bf2f(h));
    }
    *(uint4*)(dhe + (size_t)(n0 + n) * K + k0 + wc) = hh.u;
    if constexpr (SPLIT) *(uint4*)(dle + (size_t)(n0 + n) * K + k0 + wc) = ll.u;
  }
}

// ---------------- gateup GEMM v3: 128x(64g+64u) tile, global_load_lds staging ----------------
template <bool SPLIT>
__global__ __launch_bounds__(256) void gateup3_kernel(
    const unsigned short* __restrict__ xh, const unsigned short* __restrict__ xl,
    const unsigned short* __restrict__ Wh, const unsigned short* __restrict__ Wl,
    const int* __restrict__ cnt, const int* __restrict__ off,
    const int* __restrict__ tokList, unsigned short* __restrict__ actH,
    unsigned short* __restrict__ actL) {
  const int e = blockIdx.z;
  const int M = cnt[e];
  const int m0 = blockIdx.x * 128;
  if (m0 >= M) return;
  const int n0 = blockIdx.y * 64;
  const int tid = threadIdx.x;
  const int lane = tid & 63, wv = tid >> 6;

  // unpadded: row stride 32 ushorts = 64B (required by global_load_lds)
  __shared__ __align__(16) unsigned short sAh[128][32];
  __shared__ __align__(16) unsigned short sAl[SPLIT ? 128 : 1][32];
  __shared__ __align__(16) unsigned short sGh[64][32];
  __shared__ __align__(16) unsigned short sGl[SPLIT ? 64 : 1][32];
  __shared__ __align__(16) unsigned short sUh[64][32];
  __shared__ __align__(16) unsigned short sUl[SPLIT ? 64 : 1][32];

  // staging addresses: one wave-instr covers 16 rows x 64B
  const int r16 = lane >> 2;       // row within 16-group
  const int ch = (lane & 3) * 8;   // 16B chunk (ushort offset)
  int rA0 = m0 + wv * 32 + r16;       if (rA0 >= M) rA0 = M - 1;
  int rA1 = m0 + wv * 32 + 16 + r16;  if (rA1 >= M) rA1 = M - 1;
  const size_t a0 = (size_t)tokList[e * Tc + rA0] * Hc + ch;
  const size_t a1 = (size_t)tokList[e * Tc + rA1] * Hc + ch;
  const int nrow = n0 + wv * 16 + r16;
  const size_t gb = ((size_t)e * 4096 + nrow) * Hc + ch;
  const size_t ub = ((size_t)e * 4096 + 2048 + nrow) * Hc + ch;
  unsigned short* lA0 = &sAh[wv * 32][0];
  unsigned short* lA1 = &sAh[wv * 32 + 16][0];
  unsigned short* lG = &sGh[wv * 16][0];
  unsigned short* lU = &sUh[wv * 16][0];
  unsigned short* lA0l = &sAl[SPLIT ? wv * 32 : 0][0];
  unsigned short* lA1l = &sAl[SPLIT ? wv * 32 + 16 : 0][0];
  unsigned short* lGl = &sGl[SPLIT ? wv * 16 : 0][0];
  unsigned short* lUl = &sUl[SPLIT ? wv * 16 : 0][0];

  f32x4 accg[4][2], accu[4][2];
#pragma unroll
  for (int i = 0; i < 4; ++i)
#pragma unroll
    for (int j = 0; j < 2; ++j) {
      accg[i][j] = f32x4{0.f, 0.f, 0.f, 0.f};
      accu[i][j] = f32x4{0.f, 0.f, 0.f, 0.f};
    }

  const int wm = wv >> 1, wn = wv & 1;
  const int q = lane >> 4, mr = lane & 15;

  for (int k0 = 0; k0 < Hc; k0 += 32) {
    gl2lds16(xh + a0 + k0, lA0);
    gl2lds16(xh + a1 + k0, lA1);
    gl2lds16(Wh + gb + k0, lG);
    gl2lds16(Wh + ub + k0, lU);
    if constexpr (SPLIT) {
      gl2lds16(xl + a0 + k0, lA0l);
      gl2lds16(xl + a1 + k0, lA1l);
      gl2lds16(Wl + gb + k0, lGl);
      gl2lds16(Wl + ub + k0, lUl);
    }
    __syncthreads();  // drains vmcnt (loads landed) + barrier

    bf16x8 ah[4], al[4];
#pragma unroll
    for (int mt = 0; mt < 4; ++mt) {
      ah[mt] = ldfrag(&sAh[wm * 64 + mt * 16 + mr][q * 8]);
      if constexpr (SPLIT) al[mt] = ldfrag(&sAl[wm * 64 + mt * 16 + mr][q * 8]);
    }
#pragma unroll
    for (int nt = 0; nt < 2; ++nt) {
      const int bc = wn * 32 + nt * 16 + mr;
      const bf16x8 gh = ldfrag(&sGh[bc][q * 8]);
      const bf16x8 uh = ldfrag(&sUh[bc][q * 8]);
      bf16x8 gl, ul;
      if constexpr (SPLIT) {
        gl = ldfrag(&sGl[bc][q * 8]);
        ul = ldfrag(&sUl[bc][q * 8]);
      }
#pragma unroll
      for (int mt = 0; mt < 4; ++mt) {
        accg[mt][nt] = __builtin_amdgcn_mfma_f32_16x16x32_bf16(ah[mt], gh, accg[mt][nt], 0, 0, 0);
        accu[mt][nt] = __builtin_amdgcn_mfma_f32_16x16x32_bf16(ah[mt], uh, accu[mt][nt], 0, 0, 0);
        if constexpr (SPLIT) {
          accg[mt][nt] = __builtin_amdgcn_mfma_f32_16x16x32_bf16(ah[mt], gl, accg[mt][nt], 0, 0, 0);
          accg[mt][nt] = __builtin_amdgcn_mfma_f32_16x16x32_bf16(al[mt], gh, accg[mt][nt], 0, 0, 0);
          accu[mt][nt] = __builtin_amdgcn_mfma_f32_16x16x32_bf16(ah[mt], ul, accu[mt][nt], 0, 0, 0);
          accu[mt][nt] = __builtin_amdgcn_mfma_f32_16x16x32_bf16(al[mt], uh, accu[mt][nt], 0, 0, 0);
        }
      }
    }
    __syncthreads();  // all waves done reading LDS before next iter overwrites
  }

  const int valid = M - m0;
  const int rowbase = off[e] + m0;
#pragma unroll
  for (int mt = 0; mt < 4; ++mt)
#pragma unroll
    for (int nt = 0; nt < 2; ++nt)
#pragma unroll
      for (int r = 0; r < 4; ++r) {
        const int lrow = wm * 64 + mt * 16 + q * 4 + r;
        if (lrow < valid) {
          const float g = accg[mt][nt][r];
          const float u = accu[mt][nt][r];
          const float a = (g / (1.f + expf(-g))) * u;
          const int col = n0 + wn * 32 + nt * 16 + mr;
          const size_t idx = (size_t)(rowbase + lrow) * Ic + col;
          const unsigned short h = f2bf(a);
          actH[idx] = h;
          if constexpr (SPLIT) actL[idx] = f2bf(a - bf2f(h));
        }
      }
}

// ---------------- down GEMM v3: 128x64 tile, global_load_lds staging ----------------
template <bool SPLIT>
__global__ __launch_bounds__(256) void down3_kernel(
    const unsigned short* __restrict__ actH, const unsigned short* __restrict__ actL,
    const unsigned short* __restrict__ Wh, const unsigned short* __restrict__ Wl,
    const int* __restrict__ cnt, const int* __restrict__ off,
    const int* __restrict__ tokList, const float* __restrict__ wList,
    float* __restrict__ out) {
  const int e = blockIdx.z;
  const int M = cnt[e];
  const int m0 = blockIdx.x * 128;
  if (m0 >= M) return;
  const int n0 = blockIdx.y * 64;
  const int tid = threadIdx.x;
  const int lane = tid & 63, wv = tid >> 6;

  __shared__ __align__(16) unsigned short sAh[128][32];
  __shared__ __align__(16) unsigned short sAl[SPLIT ? 128 : 1][32];
  __shared__ __align__(16) unsigned short sBh[64][32];
  __shared__ __align__(16) unsigned short sBl[SPLIT ? 64 : 1][32];
  __shared__ int sTok[128];
  __shared__ float sW[128];

  if (tid < 128) {
    int r = m0 + tid;
    int rc = r < M ? r : M - 1;
    sTok[tid] = tokList[e * Tc + rc];
    sW[tid] = wList[e * Tc + rc];
  }

  const int r16 = lane >> 2;
  const int ch = (lane & 3) * 8;
  int rA0 = m0 + wv * 32 + r16;       if (rA0 >= M) rA0 = M - 1;
  int rA1 = m0 + wv * 32 + 16 + r16;  if (rA1 >= M) rA1 = M - 1;
  const size_t a0 = (size_t)(off[e] + rA0) * Ic + ch;
  const size_t a1 = (size_t)(off[e] + rA1) * Ic + ch;
  const size_t bb = ((size_t)e * Hc + n0 + wv * 16 + r16) * Ic + ch;
  unsigned short* lA0 = &sAh[wv * 32][0];
  unsigned short* lA1 = &sAh[wv * 32 + 16][0];
  unsigned short* lB = &sBh[wv * 16][0];
  unsigned short* lA0l = &sAl[SPLIT ? wv * 32 : 0][0];
  unsigned short* lA1l = &sAl[SPLIT ? wv * 32 + 16 : 0][0];
  unsigned short* lBl = &sBl[SPLIT ? wv * 16 : 0][0];

  f32x4 acc[4][2];
#pragma unroll
  for (int i = 0; i < 4; ++i)
#pragma unroll
    for (int j = 0; j < 2; ++j) acc[i][j] = f32x4{0.f, 0.f, 0.f, 0.f};

  const int wm = wv >> 1, wn = wv & 1;
  const int q = lane >> 4, mr = lane & 15;

  for (int k0 = 0; k0 < Ic; k0 += 32) {
    gl2lds16(actH + a0 + k0, lA0);
    gl2lds16(actH + a1 + k0, lA1);
    gl2lds16(Wh + bb + k0, lB);
    if constexpr (SPLIT) {
      gl2lds16(actL + a0 + k0, lA0l);
      gl2lds16(actL + a1 + k0, lA1l);
      gl2lds16(Wl + bb + k0, lBl);
    }
    __syncthreads();

    bf16x8 ah[4], al[4];
#pragma unroll
    for (int mt = 0; mt < 4; ++mt) {
      ah[mt] = ldfrag(&sAh[wm * 64 + mt * 16 + mr][q * 8]);
      if constexpr (SPLIT) al[mt] = ldfrag(&sAl[wm * 64 + mt * 16 + mr][q * 8]);
    }
#pragma unroll
    for (int nt = 0; nt < 2; ++nt) {
      const int bc = wn * 32 + nt * 16 + mr;
      const bf16x8 bh = ldfrag(&sBh[bc][q * 8]);
      bf16x8 bl;
      if constexpr (SPLIT) bl = ldfrag(&sBl[bc][q * 8]);
#pragma unroll
      for (int mt = 0; mt < 4; ++mt) {
        acc[mt][nt] = __builtin_amdgcn_mfma_f32_16x16x32_bf16(ah[mt], bh, acc[mt][nt], 0, 0, 0);
        if constexpr (SPLIT) {
          acc[mt][nt] = __builtin_amdgcn_mfma_f32_16x16x32_bf16(ah[mt], bl, acc[mt][nt], 0, 0, 0);
          acc[mt][nt] = __builtin_amdgcn_mfma_f32_16x16x32_bf16(al[mt], bh, acc[mt][nt], 0, 0, 0);
        }
      }
    }
    __syncthreads();
  }

  const int valid = M - m0;
#pragma unroll
  for (int mt = 0; mt < 4; ++mt)
#pragma unroll
    for (int nt = 0; nt < 2; ++nt)
#pragma unroll
      for (int r = 0; r < 4; ++r) {
        const int lrow = wm * 64 + mt * 16 + q * 4 + r;
        if (lrow < valid) {
          const int col = n0 + wn * 32 + nt * 16 + mr;
          atomicAdd(&out[(size_t)sTok[lrow] * Hc + col], sW[lrow] * acc[mt][nt][r]);
        }
      }
}

// ================= round-1 fallback kernels (used only if ws too small) =================
template <bool SPLIT>
__global__ __launch_bounds__(256) void gateup_fb(
    const unsigned short* __restrict__ xh, const unsigned short* __restrict__ xl,
    const float* __restrict__ gw, const int* __restrict__ cnt, const int* __restrict__ off,
    const int* __restrict__ tokList, unsigned short* __restrict__ actH,
    unsigned short* __restrict__ actL) {
  const int e = blockIdx.z;
  const int M = cnt[e];
  const int m0 = blockIdx.x * 64;
  if (m0 >= M) return;
  const int n0 = blockIdx.y * 64;
  const float* Bg = gw + (size_t)e * (Hc * 2 * Ic) + n0;
  const int tid = threadIdx.x;
  __shared__ __align__(16) unsigned short sAh[64][40];
  __shared__ __align__(16) unsigned short sAl[SPLIT ? 64 : 1][40];
  __shared__ __align__(16) unsigned short sBgh[64][40];
  __shared__ __align__(16) unsigned short sBgl[SPLIT ? 64 : 1][40];
  __shared__ __align__(16) unsigned short sBuh[64][40];
  __shared__ __align__(16) unsigned short sBul[SPLIT ? 64 : 1][40];
  const int ar = tid >> 2;
  const int ak = (tid & 3) * 8;
  int arow = m0 + ar;
  if (arow >= M) arow = M - 1;
  const size_t abase = (size_t)tokList[e * Tc + arow] * Hc + ak;
  const int bn = tid & 63;
  const int bk = (tid >> 6) * 8;
  const float* bpg = Bg + (size_t)bk * (2 * Ic) + bn;
  const float* bpu = bpg + Ic;
  f32x4 accg[4], accu[4];
#pragma unroll
  for (int i = 0; i < 4; ++i) {
    accg[i] = f32x4{0.f, 0.f, 0.f, 0.f};
    accu[i] = f32x4{0.f, 0.f, 0.f, 0.f};
  }
  const int lane = tid & 63, wv = tid >> 6;
  const int q = lane >> 4, mr = lane & 15;
  const int nc = wv * 16 + (lane & 15);
  for (int k0 = 0; k0 < Hc; k0 += 32) {
    __syncthreads();
    *(uint4*)&sAh[ar][ak] = *(const uint4*)(xh + abase + k0);
    if constexpr (SPLIT) *(uint4*)&sAl[ar][ak] = *(const uint4*)(xl + abase + k0);
    union { unsigned short s[8]; uint4 u; } hg, lg, hu, lu;
#pragma unroll
    for (int j = 0; j < 8; ++j) {
      const float vg = bpg[(size_t)(k0 + j) * (2 * Ic)];
      unsigned short h = f2bf(vg);
      hg.s[j] = h;
      if constexpr (SPLIT) lg.s[j] = f2bf(vg - bf2f(h));
      const float vu = bpu[(size_t)(k0 + j) * (2 * Ic)];
      h = f2bf(vu);
      hu.s[j] = h;
      if constexpr (SPLIT) lu.s[j] = f2bf(vu - bf2f(h));
    }
    *(uint4*)&sBgh[bn][bk] = hg.u;
    *(uint4*)&sBuh[bn][bk] = hu.u;
    if constexpr (SPLIT) {
      *(uint4*)&sBgl[bn][bk] = lg.u;
      *(uint4*)&sBul[bn][bk] = lu.u;
    }
    __syncthreads();
    bf16x8 a_h[4], a_l[4];
#pragma unroll
    for (int mt = 0; mt < 4; ++mt) {
      a_h[mt] = ldfrag(&sAh[mt * 16 + mr][q * 8]);
      if constexpr (SPLIT) a_l[mt] = ldfrag(&sAl[mt * 16 + mr][q * 8]);
    }
    const bf16x8 bgh = ldfrag(&sBgh[nc][q * 8]);
    const bf16x8 buh = ldfrag(&sBuh[nc][q * 8]);
    bf16x8 bgl, bul;
    if constexpr (SPLIT) {
      bgl = ldfrag(&sBgl[nc][q * 8]);
      bul = ldfrag(&sBul[nc][q * 8]);
    }
#pragma unroll
    for (int mt = 0; mt < 4; ++mt) {
      accg[mt] = __builtin_amdgcn_mfma_f32_16x16x32_bf16(a_h[mt], bgh, accg[mt], 0, 0, 0);
      accu[mt] = __builtin_amdgcn_mfma_f32_16x16x32_bf16(a_h[mt], buh, accu[mt], 0, 0, 0);
      if constexpr (SPLIT) {
        accg[mt] = __builtin_amdgcn_mfma_f32_16x16x32_bf16(a_h[mt], bgl, accg[mt], 0, 0, 0);
        accg[mt] = __builtin_amdgcn_mfma_f32_16x16x32_bf16(a_l[mt], bgh, accg[mt], 0, 0, 0);
        accu[mt] = __builtin_amdgcn_mfma_f32_16x16x32_bf16(a_h[mt], bul, accu[mt], 0, 0, 0);
        accu[mt] = __builtin_amdgcn_mfma_f32_16x16x32_bf16(a_l[mt], buh, accu[mt], 0, 0, 0);
      }
    }
  }
  const int valid = M - m0;
  const int rowbase = off[e] + m0;
#pragma unroll
  for (int mt = 0; mt < 4; ++mt)
#pragma unroll
    for (int r = 0; r < 4; ++r) {
      const int row = mt * 16 + q * 4 + r;
      if (row < valid) {
        const float g = accg[mt][r];
        const float u = accu[mt][r];
        const float a = (g / (1.f + expf(-g))) * u;
        const size_t idx = (size_t)(rowbase + row) * Ic + (n0 + nc);
        const unsigned short h = f2bf(a);
        actH[idx] = h;
        if constexpr (SPLIT) actL[idx] = f2bf(a - bf2f(h));
      }
    }
}

template <bool SPLIT>
__global__ __launch_bounds__(256) void down_fb(
    const unsigned short* __restrict__ actH, const unsigned short* __restrict__ actL,
    const float* __restrict__ dw, const int* __restrict__ cnt, const int* __restrict__ off,
    const int* __restrict__ tokList, const float* __restrict__ wList,
    float* __restrict__ out) {
  const int e = blockIdx.z;
  const int M = cnt[e];
  const int m0 = blockIdx.x * 64;
  if (m0 >= M) return;
  const int n0 = blockIdx.y * 64;
  const float* B = dw + (size_t)e * (Ic * Hc) + n0;
  const int tid = threadIdx.x;
  __shared__ __align__(16) unsigned short sAh[64][40];
  __shared__ __align__(16) unsigned short sAl[SPLIT ? 64 : 1][40];
  __shared__ __align__(16) unsigned short sBh[64][40];
  __shared__ __align__(16) unsigned short sBl[SPLIT ? 64 : 1][40];
  __shared__ int sTok[64];
  __shared__ float sW[64];
  if (tid < 64) {
    int r = m0 + tid;
    int rc = r < M ? r : M - 1;
    sTok[tid] = tokList[e * Tc + rc];
    sW[tid] = wList[e * Tc + rc];
  }
  const int ar = tid >> 2;
  const int ak = (tid & 3) * 8;
  int arow = m0 + ar;
  if (arow >= M) arow = M - 1;
  const size_t abase = (size_t)(off[e] + arow) * Ic + ak;
  const int bn = tid & 63;
  const int bk = (tid >> 6) * 8;
  const float* bp = B + (size_t)bk * Hc + bn;
  f32x4 acc[4];
#pragma unroll
  for (int i = 0; i < 4; ++i) acc[i] = f32x4{0.f, 0.f, 0.f, 0.f};
  const int lane = tid & 63, wv = tid >> 6;
  const int q = lane >> 4, mr = lane & 15;
  const int nc = wv * 16 + (lane & 15);
  for (int k0 = 0; k0 < Ic; k0 += 32) {
    __syncthreads();
    *(uint4*)&sAh[ar][ak] = *(const uint4*)(actH + abase + k0);
    if constexpr (SPLIT) *(uint4*)&sAl[ar][ak] = *(const uint4*)(actL + abase + k0);
    union { unsigned short s[8]; uint4 u; } hb, lb;
#pragma unroll
    for (int j = 0; j < 8; ++j) {
      const float v = bp[(size_t)(k0 + j) * Hc];
      const unsigned short h = f2bf(v);
      hb.s[j] = h;
      if constexpr (SPLIT) lb.s[j] = f2bf(v - bf2f(h));
    }
    *(uint4*)&sBh[bn][bk] = hb.u;
    if constexpr (SPLIT) *(uint4*)&sBl[bn][bk] = lb.u;
    __syncthreads();
    bf16x8 a_h[4], a_l[4];
#pragma unroll
    for (int mt = 0; mt < 4; ++mt) {
      a_h[mt] = ldfrag(&sAh[mt * 16 + mr][q * 8]);
      if constexpr (SPLIT) a_l[mt] = ldfrag(&sAl[mt * 16 + mr][q * 8]);
    }
    const bf16x8 b_h = ldfrag(&sBh[nc][q * 8]);
    bf16x8 b_l;
    if constexpr (SPLIT) b_l = ldfrag(&sBl[nc][q * 8]);
#pragma unroll
    for (int mt = 0; mt < 4; ++mt) {
      acc[mt] = __builtin_amdgcn_mfma_f32_16x16x32_bf16(a_h[mt], b_h, acc[mt], 0, 0, 0);
      if constexpr (SPLIT) {
        acc[mt] = __builtin_amdgcn_mfma_f32_16x16x32_bf16(a_h[mt], b_l, acc[mt], 0, 0, 0);
        acc[mt] = __builtin_amdgcn_mfma_f32_16x16x32_bf16(a_l[mt], b_h, acc[mt], 0, 0, 0);
      }
    }
  }
  const int valid = M - m0;
#pragma unroll
  for (int mt = 0; mt < 4; ++mt)
#pragma unroll
    for (int r = 0; r < 4; ++r) {
      const int row = mt * 16 + q * 4 + r;
      if (row < valid) {
        atomicAdd(&out[(size_t)sTok[row] * Hc + (n0 + nc)], sW[row] * acc[mt][r]);
      }
    }
}

// ---------------- host ----------------
extern "C" void kernel_launch(void* const* d_in, const int* in_sizes, int n_in, void* d_out,
                              int out_size, void* d_ws, size_t ws_size, hipStream_t stream) {
  const float* x_in = (const float*)d_in[0];
  const float* rw = (const float*)d_in[1];
  const float* guw = (const float*)d_in[2];
  const float* dnw = (const float*)d_in[3];
  float* out = (float*)d_out;
  float* logits_base = out + (size_t)Tc * Hc;

  uint8_t* w = (uint8_t*)d_ws;
  float* x1 = (float*)w;                     w += (size_t)Tc * Hc * 4;
  unsigned short* xh = (unsigned short*)w;   w += (size_t)Tc * Hc * 2;
  unsigned short* xl = (unsigned short*)w;   w += (size_t)Tc * Hc * 2;
  unsigned short* actH = (unsigned short*)w; w += (size_t)Tc * 2 * Ic * 2;
  unsigned short* actL = (unsigned short*)w; w += (size_t)Tc * 2 * Ic * 2;
  int* tokList = (int*)w;                    w += (size_t)Ec * Tc * 4;
  float* wList = (float*)w;                  w += (size_t)Ec * Tc * 4;
  int* cnt0 = (int*)w;                       w += 64;
  int* cnt1 = (int*)w;                       w += 64;
  int* off = (int*)w;                        w += 64;
  const size_t GU_SZ = (size_t)Ec * 4096 * Hc;  // elements
  const size_t DN_SZ = (size_t)Ec * Hc * Ic;
  unsigned short* WTh = (unsigned short*)w;
  unsigned short* WTl = WTh + GU_SZ;
  unsigned short* WdTh = WTh;
  unsigned short* WdTl = WTh + DN_SZ;
  const size_t required = ((uint8_t*)(WTh + 2 * GU_SZ)) - (uint8_t*)d_ws;

  hipMemsetAsync(cnt0, 0, 192, stream);
  hipMemsetAsync(x1, 0, (size_t)Tc * Hc * 4, stream);
  hipMemsetAsync(out, 0, (size_t)Tc * Hc * 4, stream);

  const float* rw1 = rw + (size_t)Hc * Ec;
  const float* guw1 = guw + (size_t)Ec * Hc * 2 * Ic;
  const float* dnw1 = dnw + (size_t)Ec * Ic * Hc;

  if (ws_size >= required) {
    // ---- layer 0 (split-bf16) ----
    router_kernel<<<Tc, 256, 0, stream>>>(x_in, rw, logits_base);
    topk_kernel<<<Tc / 256, 256, 0, stream>>>(logits_base, cnt0, tokList, wList);
    offsets_kernel<<<1, 64, 0, stream>>>(cnt0, off);
    convert_kernel<<<(Tc * Hc) / 256, 256, 0, stream>>>(x_in, xh, xl);
    transW_kernel<true><<<dim3(64, 16, Ec), 256, 0, stream>>>(guw, WTh, WTl, Hc, 2 * Ic);
    gateup3_kernel<true><<<dim3(32, 32, Ec), 256, 0, stream>>>(xh, xl, WTh, WTl, cnt0, off,
                                                               tokList, actH, actL);
    transW_kernel<true><<<dim3(16, 32, Ec), 256, 0, stream>>>(dnw, WdTh, WdTl, Ic, Hc);
    down3_kernel<true><<<dim3(32, 16, Ec), 256, 0, stream>>>(actH, actL, WdTh, WdTl, cnt0, off,
                                                             tokList, wList, x1);
    // ---- layer 1 (plain bf16) ----
    router_kernel<<<Tc, 256, 0, stream>>>(x1, rw1, logits_base + (size_t)Tc * Ec);
    topk_kernel<<<Tc / 256, 256, 0, stream>>>(logits_base + (size_t)Tc * Ec, cnt1, tokList, wList);
    offsets_kernel<<<1, 64, 0, stream>>>(cnt1, off);
    convert_kernel<<<(Tc * Hc) / 256, 256, 0, stream>>>(x1, xh, xl);
    transW_kernel<false><<<dim3(64, 16, Ec), 256, 0, stream>>>(guw1, WTh, WTl, Hc, 2 * Ic);
    gateup3_kernel<false><<<dim3(32, 32, Ec), 256, 0, stream>>>(xh, xl, WTh, WTl, cnt1, off,
                                                                tokList, actH, actL);
    transW_kernel<false><<<dim3(16, 32, Ec), 256, 0, stream>>>(dnw1, WdTh, WdTl, Ic, Hc);
    down3_kernel<false><<<dim3(32, 16, Ec), 256, 0, stream>>>(actH, actL, WdTh, WdTl, cnt1, off,
                                                              tokList, wList, out);
  } else {
    // ---- fallback: round-1 path ----
    router_kernel<<<Tc, 256, 0, stream>>>(x_in, rw, logits_base);
    topk_kernel<<<Tc / 256, 256, 0, stream>>>(logits_base, cnt0, tokList, wList);
    offsets_kernel<<<1, 64, 0, stream>>>(cnt0, off);
    convert_kernel<<<(Tc * Hc) / 256, 256, 0, stream>>>(x_in, xh, xl);
    gateup_fb<true><<<dim3(32, 32, Ec), 256, 0, stream>>>(xh, xl, guw, cnt0, off, tokList, actH, actL);
    down_fb<true><<<dim3(32, 16, Ec), 256, 0, stream>>>(actH, actL, dnw, cnt0, off, tokList, wList, x1);
    router_kernel<<<Tc, 256, 0, stream>>>(x1, rw1, logits_base + (size_t)Tc * Ec);
    topk_kernel<<<Tc / 256, 256, 0, stream>>>(logits_base + (size_t)Tc * Ec, cnt1, tokList, wList);
    offsets_kernel<<<1, 64, 0, stream>>>(cnt1, off);
    convert_kernel<<<(Tc * Hc) / 256, 256, 0, stream>>>(x1, xh, xl);
    gateup_fb<false><<<dim3(32, 32, Ec), 256, 0, stream>>>(xh, xl, guw1, cnt1, off, tokList, actH, actL);
    down_fb<false><<<dim3(32, 16, Ec), 256, 0, stream>>>(actH, actL, dnw1, cnt1, off, tokList, wList, out);
  }
}